// Round 1
// baseline (178.452 us; speedup 1.0000x reference)
//
#include <hip/hip_runtime.h>

typedef __attribute__((ext_vector_type(8))) short short8;
typedef __attribute__((ext_vector_type(4))) float f32x4;

#define DEV __device__ __forceinline__

constexpr int Bb = 2, Ss = 2048, Tt = 2048, Ee = 1024, Hh = 16, HDd = 64;
constexpr int Mm = Bb * Ss;                  // 4096 tokens
constexpr size_t NX = (size_t)Mm * Ee;       // 4194304 elems (also mask count)
constexpr size_t NW = (size_t)Ee * Ee;       // 1048576 elems

// ---- workspace layout (bytes) ----
constexpr size_t OFF_XQ   = 0;
constexpr size_t OFF_XK   = OFF_XQ + NX * 2;
constexpr size_t OFF_XV   = OFF_XK + NX * 2;
constexpr size_t OFF_WQ   = OFF_XV + NX * 2;
constexpr size_t OFF_WK   = OFF_WQ + NW * 2;
constexpr size_t OFF_WV   = OFF_WK + NW * 2;
constexpr size_t OFF_WO   = OFF_WV + NW * 2;
constexpr size_t OFF_QH   = OFF_WO + NW * 2;   // [B*H][S][64] bf16
constexpr size_t OFF_KH   = OFF_QH + NX * 2;
constexpr size_t OFF_VH   = OFF_KH + NX * 2;
constexpr size_t OFF_OB   = OFF_VH + NX * 2;   // [B][S][E] bf16 attention out
constexpr size_t OFF_FLAG = OFF_OB + NX * 2;   // int: 1 if mask has a zero
// total: 64 MiB + 4 B

DEV unsigned short f2bf(float f) {
  union { float f; unsigned u; } v; v.f = f;
  unsigned r = v.u + 0x7fffu + ((v.u >> 16) & 1u);   // RNE
  return (unsigned short)(r >> 16);
}

#define GLDS16(g, l) __builtin_amdgcn_global_load_lds(                         \
    (const __attribute__((address_space(1))) void*)(g),                        \
    (__attribute__((address_space(3))) void*)(l), 16, 0, 0)

// ============ prep: f32 -> bf16 converts + mask scan ============
__global__ __launch_bounds__(256) void prep_kernel(
    const float* __restrict__ q, const float* __restrict__ k, const float* __restrict__ v,
    const float* __restrict__ wq, const float* __restrict__ wk,
    const float* __restrict__ wv, const float* __restrict__ wo,
    const int* __restrict__ mask,
    unsigned short* __restrict__ Xq, unsigned short* __restrict__ Xk, unsigned short* __restrict__ Xv,
    unsigned short* __restrict__ Wqb, unsigned short* __restrict__ Wkb,
    unsigned short* __restrict__ Wvb, unsigned short* __restrict__ Wob,
    int* __restrict__ flagZero)
{
  constexpr size_t NXv = NX / 4, NWv = NW / 4;
  constexpr size_t tot = 4 * NXv + 4 * NWv;  // 3 X-segs + 4 W-segs + mask seg
  for (size_t u = (size_t)blockIdx.x * blockDim.x + threadIdx.x; u < tot;
       u += (size_t)gridDim.x * blockDim.x) {
    if (u < 3 * NXv) {
      const float* src; unsigned short* dst; size_t off;
      if (u < NXv)            { src = q; dst = Xq; off = u; }
      else if (u < 2 * NXv)   { src = k; dst = Xk; off = u - NXv; }
      else                    { src = v; dst = Xv; off = u - 2 * NXv; }
      float4 f = ((const float4*)src)[off];
      ushort4 o; o.x = f2bf(f.x); o.y = f2bf(f.y); o.z = f2bf(f.z); o.w = f2bf(f.w);
      ((ushort4*)dst)[off] = o;
    } else if (u < 3 * NXv + 4 * NWv) {
      size_t uu = u - 3 * NXv;
      int wsel = (int)(uu / NWv); size_t off = uu % NWv;
      const float* src = wsel == 0 ? wq : wsel == 1 ? wk : wsel == 2 ? wv : wo;
      unsigned short* dst = wsel == 0 ? Wqb : wsel == 1 ? Wkb : wsel == 2 ? Wvb : Wob;
      float4 f = ((const float4*)src)[off];
      ushort4 o; o.x = f2bf(f.x); o.y = f2bf(f.y); o.z = f2bf(f.z); o.w = f2bf(f.w);
      ((ushort4*)dst)[off] = o;
    } else {
      size_t off = u - 3 * NXv - 4 * NWv;
      int4 m = ((const int4*)mask)[off];
      if (m.x == 0 || m.y == 0 || m.z == 0 || m.w == 0) *flagZero = 1;
    }
  }
}

// ============ 128x128 GEMM core: C = A(MxK) * B(NxK)^T, bf16, m97 structure ============
DEV void gemm128(const unsigned short* __restrict__ A, const unsigned short* __restrict__ Bm,
                 unsigned short* Asm, unsigned short* Bsm, f32x4 acc[4][4], int K)
{
  const int t = threadIdx.x;
  const int w = t >> 6, lane = t & 63;
  const int l15 = lane & 15, l4 = lane >> 4;
  const int wm = w >> 1, wn = w & 1;
  const int srow = lane >> 2;          // 0..15 within wave's 16-row slab
  const int skc  = (lane & 3) * 8;     // k-chunk 0/8/16/24
#pragma unroll
  for (int mi = 0; mi < 4; ++mi)
#pragma unroll
    for (int ni = 0; ni < 4; ++ni) acc[mi][ni] = (f32x4){0.f, 0.f, 0.f, 0.f};

  for (int k0 = 0; k0 < K; k0 += 32) {
    // stage A,B tiles (128x32 bf16 each) via global_load_lds, linear LDS
    GLDS16(A  + (size_t)(w * 16 + srow) * K + k0 + skc,        Asm + w * 512);
    GLDS16(A  + (size_t)(64 + w * 16 + srow) * K + k0 + skc,   Asm + 2048 + w * 512);
    GLDS16(Bm + (size_t)(w * 16 + srow) * K + k0 + skc,        Bsm + w * 512);
    GLDS16(Bm + (size_t)(64 + w * 16 + srow) * K + k0 + skc,   Bsm + 2048 + w * 512);
    __syncthreads();
    short8 af[4], bf[4];
#pragma unroll
    for (int mi = 0; mi < 4; ++mi)
      af[mi] = *(const short8*)&Asm[(wm * 64 + mi * 16 + l15) * 32 + l4 * 8];
#pragma unroll
    for (int ni = 0; ni < 4; ++ni)
      bf[ni] = *(const short8*)&Bsm[(wn * 64 + ni * 16 + l15) * 32 + l4 * 8];
#pragma unroll
    for (int mi = 0; mi < 4; ++mi)
#pragma unroll
      for (int ni = 0; ni < 4; ++ni)
        acc[mi][ni] = __builtin_amdgcn_mfma_f32_16x16x32_bf16(af[mi], bf[ni], acc[mi][ni], 0, 0, 0);
    __syncthreads();
  }
}

// ============ QKV projection: y = X @ W^T + b, epilogue -> head layout bf16 ============
__global__ __launch_bounds__(256) void gemm_qkv(
    const unsigned short* __restrict__ Xq, const unsigned short* __restrict__ Xk,
    const unsigned short* __restrict__ Xv,
    const unsigned short* __restrict__ Wqb, const unsigned short* __restrict__ Wkb,
    const unsigned short* __restrict__ Wvb,
    const float* __restrict__ bq, const float* __restrict__ bk, const float* __restrict__ bv,
    unsigned short* __restrict__ Qh, unsigned short* __restrict__ Kh, unsigned short* __restrict__ Vh)
{
  __shared__ unsigned short Asm[128 * 32], Bsm[128 * 32];
  const int z = blockIdx.z;
  const unsigned short* A  = (z == 0) ? Xq  : (z == 1) ? Xk  : Xv;
  const unsigned short* Bw = (z == 0) ? Wqb : (z == 1) ? Wkb : Wvb;
  const float* bias        = (z == 0) ? bq  : (z == 1) ? bk  : bv;
  unsigned short* Out      = (z == 0) ? Qh  : (z == 1) ? Kh  : Vh;
  const int by = blockIdx.y, bx = blockIdx.x;
  f32x4 acc[4][4];
  gemm128(A + (size_t)by * 128 * Ee, Bw + (size_t)bx * 128 * Ee, Asm, Bsm, acc, Ee);
  const int t = threadIdx.x, w = t >> 6, lane = t & 63, l15 = lane & 15, l4 = lane >> 4;
  const int wm = w >> 1, wn = w & 1;
#pragma unroll
  for (int ni = 0; ni < 4; ++ni) {
    int col = bx * 128 + wn * 64 + ni * 16 + l15;
    float bcol = bias[col];
    int h = col >> 6, hd = col & 63;
#pragma unroll
    for (int mi = 0; mi < 4; ++mi) {
#pragma unroll
      for (int r = 0; r < 4; ++r) {
        int row = by * 128 + wm * 64 + mi * 16 + l4 * 4 + r;
        int b = row >> 11, s = row & 2047;
        Out[(((size_t)(b * Hh + h)) * Ss + s) * HDd + hd] = f2bf(acc[mi][ni][r] + bcol);
      }
    }
  }
}

// ============ output projection: out = Ob @ Wo^T + bo (f32 out) ============
__global__ __launch_bounds__(256) void gemm_out(
    const unsigned short* __restrict__ Ob, const unsigned short* __restrict__ Wob,
    const float* __restrict__ bo, float* __restrict__ out)
{
  __shared__ unsigned short Asm[128 * 32], Bsm[128 * 32];
  const int by = blockIdx.y, bx = blockIdx.x;
  f32x4 acc[4][4];
  gemm128(Ob + (size_t)by * 128 * Ee, Wob + (size_t)bx * 128 * Ee, Asm, Bsm, acc, Ee);
  const int t = threadIdx.x, w = t >> 6, lane = t & 63, l15 = lane & 15, l4 = lane >> 4;
  const int wm = w >> 1, wn = w & 1;
#pragma unroll
  for (int ni = 0; ni < 4; ++ni) {
    int col = bx * 128 + wn * 64 + ni * 16 + l15;
    float bcol = bo[col];
#pragma unroll
    for (int mi = 0; mi < 4; ++mi) {
#pragma unroll
      for (int r = 0; r < 4; ++r) {
        int row = by * 128 + wm * 64 + mi * 16 + l4 * 4 + r;
        out[(size_t)row * Ee + col] = acc[mi][ni][r] + bcol;
      }
    }
  }
}

// ============ flash attention: per (b,h), 128 q-rows/block, KV tiles of 64 ============
// swapped QK^T: scores^T = mfma(A=K_tile, B=Q)  ->  lane holds col s = l&15, rows t
__global__ __launch_bounds__(256) void attn_kernel(
    const unsigned short* __restrict__ Qh, const unsigned short* __restrict__ Kh,
    const unsigned short* __restrict__ Vh, const int* __restrict__ mask,
    const int* __restrict__ flagZero, unsigned short* __restrict__ Ob)
{
  __shared__ unsigned short Ksm[64 * 64];     // [t][d], XOR-swizzled rows
  __shared__ unsigned short Vsm[64 * 64];     // V^T: [hd][t], XOR-swizzled rows
  __shared__ unsigned short Psm[4][32 * 64];  // per-wave P [s][t], XOR-swizzled rows
  const float NEG_INF = -__builtin_inff();
  const int bh = blockIdx.y, qt = blockIdx.x;
  const int t = threadIdx.x, w = t >> 6, lane = t & 63;
  const int l15 = lane & 15, l4 = lane >> 4;
  const bool useMask = (*flagZero != 0);
  const size_t bhBase = (size_t)bh * Ss * HDd;
  const int s0 = qt * 128 + w * 32;

  // Q fragments (B-operand of swapped QK^T): Q[s0+sb*16+l15][dh*32 + l4*8 + j]
  short8 qf[2][2];
#pragma unroll
  for (int sb = 0; sb < 2; ++sb)
#pragma unroll
    for (int dh = 0; dh < 2; ++dh)
      qf[sb][dh] = *(const short8*)&Qh[bhBase + (size_t)(s0 + sb * 16 + l15) * 64 + dh * 32 + l4 * 8];

  f32x4 o[2][4];
#pragma unroll
  for (int rb = 0; rb < 2; ++rb)
#pragma unroll
    for (int cb = 0; cb < 4; ++cb) o[rb][cb] = (f32x4){0.f, 0.f, 0.f, 0.f};
  float m_r[2] = {NEG_INF, NEG_INF}, l_r[2] = {0.f, 0.f};

  const int vrow = t & 63;            // t index for V staging
  const int hd0  = (t >> 6) * 16;     // this wave's hd slab

  for (int kt = 0; kt < Tt; kt += 64) {
    // ---- stage K (global_load_lds, pre-swizzled source; read-side XOR matches) ----
#pragma unroll
    for (int i = 0; i < 2; ++i) {
      int row = i * 32 + w * 8 + (lane >> 3);
      int ch  = (lane & 7) ^ (row & 7);
      GLDS16(Kh + bhBase + (size_t)(kt + row) * 64 + ch * 8, Ksm + i * 2048 + w * 512);
    }
    // ---- stage V^T (reg-staged, swizzled scatter writes) ----
    {
      const unsigned short* vsrc = Vh + bhBase + (size_t)(kt + vrow) * 64 + hd0;
      short8 v0 = *(const short8*)vsrc;
      short8 v1 = *(const short8*)(vsrc + 8);
#pragma unroll
      for (int j = 0; j < 8; ++j) {
        int hd = hd0 + j;
        Vsm[hd * 64 + (((vrow * 2) ^ ((hd & 7) << 4)) >> 1)] = (unsigned short)v0[j];
      }
#pragma unroll
      for (int j = 0; j < 8; ++j) {
        int hd = hd0 + 8 + j;
        Vsm[hd * 64 + (((vrow * 2) ^ ((hd & 7) << 4)) >> 1)] = (unsigned short)v1[j];
      }
    }
    __syncthreads();

    // ---- QK^T (scores^T): sc[tb][sb], rows t, cols s ----
    f32x4 sc[4][2];
#pragma unroll
    for (int tb = 0; tb < 4; ++tb)
#pragma unroll
      for (int sb = 0; sb < 2; ++sb) sc[tb][sb] = (f32x4){0.f, 0.f, 0.f, 0.f};
#pragma unroll
    for (int tb = 0; tb < 4; ++tb) {
      int trow = tb * 16 + l15;
      short8 kf0 = *(const short8*)&Ksm[trow * 64 + ((((0 * 64) + l4 * 16) ^ ((trow & 7) << 4)) >> 1)];
      short8 kf1 = *(const short8*)&Ksm[trow * 64 + (((64 + l4 * 16) ^ ((trow & 7) << 4)) >> 1)];
#pragma unroll
      for (int sb = 0; sb < 2; ++sb) {
        sc[tb][sb] = __builtin_amdgcn_mfma_f32_16x16x32_bf16(kf0, qf[sb][0], sc[tb][sb], 0, 0, 0);
        sc[tb][sb] = __builtin_amdgcn_mfma_f32_16x16x32_bf16(kf1, qf[sb][1], sc[tb][sb], 0, 0, 0);
      }
    }
    // scale
#pragma unroll
    for (int tb = 0; tb < 4; ++tb)
#pragma unroll
      for (int sb = 0; sb < 2; ++sb)
#pragma unroll
        for (int r = 0; r < 4; ++r) sc[tb][sb][r] *= 0.125f;
    if (useMask) {
#pragma unroll
      for (int tb = 0; tb < 4; ++tb)
#pragma unroll
        for (int sb = 0; sb < 2; ++sb)
#pragma unroll
          for (int r = 0; r < 4; ++r) {
            int sg = s0 + sb * 16 + l15;
            int tg = kt + tb * 16 + l4 * 4 + r;
            if (mask[(size_t)sg * Tt + tg] == 0) sc[tb][sb][r] = NEG_INF;
          }
    }
    // ---- online softmax (stats live in the 4 lanes sharing l15) ----
    float al[2];
#pragma unroll
    for (int sb = 0; sb < 2; ++sb) {
      float tmax = NEG_INF;
#pragma unroll
      for (int tb = 0; tb < 4; ++tb)
#pragma unroll
        for (int r = 0; r < 4; ++r) tmax = fmaxf(tmax, sc[tb][sb][r]);
      tmax = fmaxf(tmax, __shfl_xor(tmax, 16));
      tmax = fmaxf(tmax, __shfl_xor(tmax, 32));
      float mnew = fmaxf(m_r[sb], tmax);
      bool dead = (mnew == NEG_INF);
      float msafe = dead ? 0.f : mnew;
      float alpha = dead ? 1.f : __expf(m_r[sb] - mnew);
      float psum = 0.f;
      int sr = sb * 16 + l15;
#pragma unroll
      for (int tb = 0; tb < 4; ++tb) {
        float p0 = __expf(sc[tb][sb][0] - msafe);
        float p1 = __expf(sc[tb][sb][1] - msafe);
        float p2 = __expf(sc[tb][sb][2] - msafe);
        float p3 = __expf(sc[tb][sb][3] - msafe);
        psum += p0 + p1 + p2 + p3;
        ushort4 pk; pk.x = f2bf(p0); pk.y = f2bf(p1); pk.z = f2bf(p2); pk.w = f2bf(p3);
        int ebase = sr * 64 + ((((tb * 16 + l4 * 4) * 2) ^ ((sr & 7) << 4)) >> 1);
        *(ushort4*)&Psm[w][ebase] = pk;
      }
      psum += __shfl_xor(psum, 16);
      psum += __shfl_xor(psum, 32);
      l_r[sb] = l_r[sb] * alpha + psum;
      m_r[sb] = mnew;
      al[sb] = alpha;
    }
    // ---- rescale O rows (redistribute alpha col-layout -> row-layout) ----
#pragma unroll
    for (int rb = 0; rb < 2; ++rb)
#pragma unroll
      for (int r = 0; r < 4; ++r) {
        float a = __shfl(al[rb], l4 * 4 + r);
#pragma unroll
        for (int cb = 0; cb < 4; ++cb) o[rb][cb][r] *= a;
      }
    asm volatile("s_waitcnt lgkmcnt(0)" ::: "memory");   // P writes -> P reads (same wave)
    // ---- PV: O += P * V ----
#pragma unroll
    for (int kh = 0; kh < 2; ++kh) {
      short8 pf[2], vf[4];
#pragma unroll
      for (int rb = 0; rb < 2; ++rb) {
        int srr = rb * 16 + l15;
        pf[rb] = *(const short8*)&Psm[w][srr * 64 + (((kh * 64 + l4 * 16) ^ ((srr & 7) << 4)) >> 1)];
      }
#pragma unroll
      for (int cb = 0; cb < 4; ++cb) {
        int hr = cb * 16 + l15;
        vf[cb] = *(const short8*)&Vsm[hr * 64 + (((kh * 64 + l4 * 16) ^ ((hr & 7) << 4)) >> 1)];
      }
#pragma unroll
      for (int rb = 0; rb < 2; ++rb)
#pragma unroll
        for (int cb = 0; cb < 4; ++cb)
          o[rb][cb] = __builtin_amdgcn_mfma_f32_16x16x32_bf16(pf[rb], vf[cb], o[rb][cb], 0, 0, 0);
    }
    __syncthreads();
  }
  // ---- epilogue: O/l -> Ob[b][s][h*64+hd] bf16 ----
  const int b = bh >> 4, h = bh & 15;
#pragma unroll
  for (int rb = 0; rb < 2; ++rb) {
    float linv = 1.0f / l_r[rb];
#pragma unroll
    for (int r = 0; r < 4; ++r) {
      float li = __shfl(linv, l4 * 4 + r);
      int srow = s0 + rb * 16 + l4 * 4 + r;
#pragma unroll
      for (int cb = 0; cb < 4; ++cb)
        Ob[((size_t)(b * Ss + srow)) * Ee + h * 64 + cb * 16 + l15] = f2bf(o[rb][cb][r] * li);
    }
  }
}

extern "C" void kernel_launch(void* const* d_in, const int* in_sizes, int n_in,
                              void* d_out, int out_size, void* d_ws, size_t ws_size,
                              hipStream_t stream) {
  const float* q   = (const float*)d_in[0];
  const float* k   = (const float*)d_in[1];
  const float* v   = (const float*)d_in[2];
  const int*  msk  = (const int*)d_in[3];
  const float* Wq  = (const float*)d_in[4];
  const float* bq  = (const float*)d_in[5];
  const float* Wk  = (const float*)d_in[6];
  const float* bk  = (const float*)d_in[7];
  const float* Wv  = (const float*)d_in[8];
  const float* bv  = (const float*)d_in[9];
  const float* Wo  = (const float*)d_in[10];
  const float* bo  = (const float*)d_in[11];
  float* out = (float*)d_out;

  char* ws = (char*)d_ws;
  unsigned short* Xq  = (unsigned short*)(ws + OFF_XQ);
  unsigned short* Xk  = (unsigned short*)(ws + OFF_XK);
  unsigned short* Xv  = (unsigned short*)(ws + OFF_XV);
  unsigned short* Wqb = (unsigned short*)(ws + OFF_WQ);
  unsigned short* Wkb = (unsigned short*)(ws + OFF_WK);
  unsigned short* Wvb = (unsigned short*)(ws + OFF_WV);
  unsigned short* Wob = (unsigned short*)(ws + OFF_WO);
  unsigned short* Qh  = (unsigned short*)(ws + OFF_QH);
  unsigned short* Kh  = (unsigned short*)(ws + OFF_KH);
  unsigned short* Vh  = (unsigned short*)(ws + OFF_VH);
  unsigned short* Ob  = (unsigned short*)(ws + OFF_OB);
  int* flagZero       = (int*)(ws + OFF_FLAG);

  hipMemsetAsync(flagZero, 0, 4, stream);
  prep_kernel<<<4096, 256, 0, stream>>>(q, k, v, Wq, Wk, Wv, Wo, msk,
                                        Xq, Xk, Xv, Wqb, Wkb, Wvb, Wob, flagZero);
  gemm_qkv<<<dim3(8, 32, 3), 256, 0, stream>>>(Xq, Xk, Xv, Wqb, Wkb, Wvb,
                                               bq, bk, bv, Qh, Kh, Vh);
  attn_kernel<<<dim3(16, 32), 256, 0, stream>>>(Qh, Kh, Vh, msk, flagZero, Ob);
  gemm_out<<<dim3(8, 32), 256, 0, stream>>>(Ob, Wob, bo, out);
}

// Round 3
// 151.572 us; speedup vs baseline: 1.1773x; 1.1773x over previous
//
#include <hip/hip_runtime.h>

typedef __attribute__((ext_vector_type(8))) short short8;
typedef __attribute__((ext_vector_type(4))) float f32x4;
typedef __attribute__((ext_vector_type(16))) float f32x16;

#define DEV __device__ __forceinline__

constexpr int Bb = 2, Ss = 2048, Tt = 2048, Ee = 1024, Hh = 16, HDd = 64;
constexpr int Mm = Bb * Ss;                  // 4096 tokens
constexpr size_t NX = (size_t)Mm * Ee;       // 4194304 elems (also mask count)
constexpr size_t NW = (size_t)Ee * Ee;       // 1048576 elems

// ---- workspace layout (bytes) ----
constexpr size_t OFF_XQ   = 0;
constexpr size_t OFF_XK   = OFF_XQ + NX * 2;
constexpr size_t OFF_XV   = OFF_XK + NX * 2;
constexpr size_t OFF_WQ   = OFF_XV + NX * 2;
constexpr size_t OFF_WK   = OFF_WQ + NW * 2;
constexpr size_t OFF_WV   = OFF_WK + NW * 2;
constexpr size_t OFF_WO   = OFF_WV + NW * 2;
constexpr size_t OFF_QH   = OFF_WO + NW * 2;   // [B*H][S][64] bf16
constexpr size_t OFF_KH   = OFF_QH + NX * 2;
constexpr size_t OFF_VH   = OFF_KH + NX * 2;
constexpr size_t OFF_OB   = OFF_VH + NX * 2;   // [B][S][E] bf16 attention out
constexpr size_t OFF_FLAG = OFF_OB + NX * 2;   // int: 1 if mask has a zero

DEV unsigned short f2bf(float f) {
  union { float f; unsigned u; } v; v.f = f;
  unsigned r = v.u + 0x7fffu + ((v.u >> 16) & 1u);   // RNE
  return (unsigned short)(r >> 16);
}

#define GLDS16(g, l) __builtin_amdgcn_global_load_lds(                         \
    (const __attribute__((address_space(1))) void*)(g),                        \
    (__attribute__((address_space(3))) void*)(l), 16, 0, 0)

// swap hi-half of a with lo-half of b. ONLY safe when a,b are distinct live
// SSA values (identical copies get register-coalesced -> self-swap bug!).
#define PLSWAP(a, b) asm("v_permlane32_swap_b32 %0, %1" : "+v"(a), "+v"(b))
#define CVTPK(d, lo, hi_) asm("v_cvt_pk_bf16_f32 %0, %1, %2" : "=v"(d) : "v"(lo), "v"(hi_))

#if __has_builtin(__builtin_amdgcn_exp2f)
#define EXP2(x) __builtin_amdgcn_exp2f(x)
#else
#define EXP2(x) exp2f(x)
#endif

// ============ prep: f32 -> bf16 converts + mask scan ============
__global__ __launch_bounds__(256) void prep_kernel(
    const float* __restrict__ q, const float* __restrict__ k, const float* __restrict__ v,
    const float* __restrict__ wq, const float* __restrict__ wk,
    const float* __restrict__ wv, const float* __restrict__ wo,
    const int* __restrict__ mask,
    unsigned short* __restrict__ Xq, unsigned short* __restrict__ Xk, unsigned short* __restrict__ Xv,
    unsigned short* __restrict__ Wqb, unsigned short* __restrict__ Wkb,
    unsigned short* __restrict__ Wvb, unsigned short* __restrict__ Wob,
    int* __restrict__ flagZero)
{
  constexpr size_t NXv = NX / 4, NWv = NW / 4;
  constexpr size_t tot = 4 * NXv + 4 * NWv;
  for (size_t u = (size_t)blockIdx.x * blockDim.x + threadIdx.x; u < tot;
       u += (size_t)gridDim.x * blockDim.x) {
    if (u < 3 * NXv) {
      const float* src; unsigned short* dst; size_t off;
      if (u < NXv)            { src = q; dst = Xq; off = u; }
      else if (u < 2 * NXv)   { src = k; dst = Xk; off = u - NXv; }
      else                    { src = v; dst = Xv; off = u - 2 * NXv; }
      float4 f = ((const float4*)src)[off];
      ushort4 o; o.x = f2bf(f.x); o.y = f2bf(f.y); o.z = f2bf(f.z); o.w = f2bf(f.w);
      ((ushort4*)dst)[off] = o;
    } else if (u < 3 * NXv + 4 * NWv) {
      size_t uu = u - 3 * NXv;
      int wsel = (int)(uu / NWv); size_t off = uu % NWv;
      const float* src = wsel == 0 ? wq : wsel == 1 ? wk : wsel == 2 ? wv : wo;
      unsigned short* dst = wsel == 0 ? Wqb : wsel == 1 ? Wkb : wsel == 2 ? Wvb : Wob;
      float4 f = ((const float4*)src)[off];
      ushort4 o; o.x = f2bf(f.x); o.y = f2bf(f.y); o.z = f2bf(f.z); o.w = f2bf(f.w);
      ((ushort4*)dst)[off] = o;
    } else {
      size_t off = u - 3 * NXv - 4 * NWv;
      int4 m = ((const int4*)mask)[off];
      if (m.x == 0 || m.y == 0 || m.z == 0 || m.w == 0) *flagZero = 1;
    }
  }
}

// ============ 128x128 GEMM core: C = A(MxK) * B(NxK)^T, bf16, m97 structure ============
DEV void gemm128(const unsigned short* __restrict__ A, const unsigned short* __restrict__ Bm,
                 unsigned short* Asm, unsigned short* Bsm, f32x4 acc[4][4], int K)
{
  const int t = threadIdx.x;
  const int w = t >> 6, lane = t & 63;
  const int l15 = lane & 15, l4 = lane >> 4;
  const int wm = w >> 1, wn = w & 1;
  const int srow = lane >> 2;
  const int skc  = (lane & 3) * 8;
#pragma unroll
  for (int mi = 0; mi < 4; ++mi)
#pragma unroll
    for (int ni = 0; ni < 4; ++ni) acc[mi][ni] = (f32x4){0.f, 0.f, 0.f, 0.f};

  for (int k0 = 0; k0 < K; k0 += 32) {
    GLDS16(A  + (size_t)(w * 16 + srow) * K + k0 + skc,        Asm + w * 512);
    GLDS16(A  + (size_t)(64 + w * 16 + srow) * K + k0 + skc,   Asm + 2048 + w * 512);
    GLDS16(Bm + (size_t)(w * 16 + srow) * K + k0 + skc,        Bsm + w * 512);
    GLDS16(Bm + (size_t)(64 + w * 16 + srow) * K + k0 + skc,   Bsm + 2048 + w * 512);
    __syncthreads();
    short8 af[4], bf[4];
#pragma unroll
    for (int mi = 0; mi < 4; ++mi)
      af[mi] = *(const short8*)&Asm[(wm * 64 + mi * 16 + l15) * 32 + l4 * 8];
#pragma unroll
    for (int ni = 0; ni < 4; ++ni)
      bf[ni] = *(const short8*)&Bsm[(wn * 64 + ni * 16 + l15) * 32 + l4 * 8];
#pragma unroll
    for (int mi = 0; mi < 4; ++mi)
#pragma unroll
      for (int ni = 0; ni < 4; ++ni)
        acc[mi][ni] = __builtin_amdgcn_mfma_f32_16x16x32_bf16(af[mi], bf[ni], acc[mi][ni], 0, 0, 0);
    __syncthreads();
  }
}

// ============ QKV projection ============
__global__ __launch_bounds__(256) void gemm_qkv(
    const unsigned short* __restrict__ Xq, const unsigned short* __restrict__ Xk,
    const unsigned short* __restrict__ Xv,
    const unsigned short* __restrict__ Wqb, const unsigned short* __restrict__ Wkb,
    const unsigned short* __restrict__ Wvb,
    const float* __restrict__ bq, const float* __restrict__ bk, const float* __restrict__ bv,
    unsigned short* __restrict__ Qh, unsigned short* __restrict__ Kh, unsigned short* __restrict__ Vh)
{
  __shared__ unsigned short Asm[128 * 32], Bsm[128 * 32];
  const int z = blockIdx.z;
  const unsigned short* A  = (z == 0) ? Xq  : (z == 1) ? Xk  : Xv;
  const unsigned short* Bw = (z == 0) ? Wqb : (z == 1) ? Wkb : Wvb;
  const float* bias        = (z == 0) ? bq  : (z == 1) ? bk  : bv;
  unsigned short* Out      = (z == 0) ? Qh  : (z == 1) ? Kh  : Vh;
  const int by = blockIdx.y, bx = blockIdx.x;
  f32x4 acc[4][4];
  gemm128(A + (size_t)by * 128 * Ee, Bw + (size_t)bx * 128 * Ee, Asm, Bsm, acc, Ee);
  const int t = threadIdx.x, w = t >> 6, lane = t & 63, l15 = lane & 15, l4 = lane >> 4;
  const int wm = w >> 1, wn = w & 1;
#pragma unroll
  for (int ni = 0; ni < 4; ++ni) {
    int col = bx * 128 + wn * 64 + ni * 16 + l15;
    float bcol = bias[col];
    int h = col >> 6, hd = col & 63;
#pragma unroll
    for (int mi = 0; mi < 4; ++mi) {
#pragma unroll
      for (int r = 0; r < 4; ++r) {
        int row = by * 128 + wm * 64 + mi * 16 + l4 * 4 + r;
        int b = row >> 11, s = row & 2047;
        Out[(((size_t)(b * Hh + h)) * Ss + s) * HDd + hd] = f2bf(acc[mi][ni][r] + bcol);
      }
    }
  }
}

// ============ output projection ============
__global__ __launch_bounds__(256) void gemm_out(
    const unsigned short* __restrict__ Ob, const unsigned short* __restrict__ Wob,
    const float* __restrict__ bo, float* __restrict__ out)
{
  __shared__ unsigned short Asm[128 * 32], Bsm[128 * 32];
  const int by = blockIdx.y, bx = blockIdx.x;
  f32x4 acc[4][4];
  gemm128(Ob + (size_t)by * 128 * Ee, Wob + (size_t)bx * 128 * Ee, Asm, Bsm, acc, Ee);
  const int t = threadIdx.x, w = t >> 6, lane = t & 63, l15 = lane & 15, l4 = lane >> 4;
  const int wm = w >> 1, wn = w & 1;
#pragma unroll
  for (int ni = 0; ni < 4; ++ni) {
    int col = bx * 128 + wn * 64 + ni * 16 + l15;
    float bcol = bo[col];
#pragma unroll
    for (int mi = 0; mi < 4; ++mi) {
#pragma unroll
      for (int r = 0; r < 4; ++r) {
        int row = by * 128 + wm * 64 + mi * 16 + l4 * 4 + r;
        out[(size_t)row * Ee + col] = acc[mi][ni][r] + bcol;
      }
    }
  }
}

// ============ flash attention v2.1: 4 warps x 32 q-rows, 32x32x16 MFMA, in-reg softmax ============
// swapped QK^T: scT = mfma(A=K, B=Q) -> lane owns q-row s = lane&31; rows t per reg:
// t = 32*tb + (r&3) + 8*(r>>2) + 4*(lane>>5)
__global__ __launch_bounds__(256) void attn_kernel(
    const unsigned short* __restrict__ Qh, const unsigned short* __restrict__ Kh,
    const unsigned short* __restrict__ Vh, const int* __restrict__ mask,
    const int* __restrict__ flagZero, unsigned short* __restrict__ Ob)
{
  __shared__ unsigned short Ks[2][64 * 64];   // [t][d], 16B-chunk XOR-swizzled by (t&7)
  __shared__ unsigned short Vt[2][64 * 72];   // V^T [hd][t], row pad +8 elems (bank rotate)
  const int bh = blockIdx.y, qt = blockIdx.x;
  const int tid = threadIdx.x, w = tid >> 6, lane = tid & 63;
  const int l31 = lane & 31, hi = lane >> 5;
  const bool useMask = (*flagZero != 0);
  const size_t bhBase = (size_t)bh * Ss * HDd;
  const int s0 = qt * 128 + w * 32;
  const float SCL = 0.18033688f;   // 0.125 * log2(e)

  // Q fragments (B-operand): Q[s0 + l31][ks*16 + hi*8 + j]
  short8 qf[4];
#pragma unroll
  for (int ks = 0; ks < 4; ++ks)
    qf[ks] = *(const short8*)&Qh[bhBase + (size_t)(s0 + l31) * 64 + ks * 16 + hi * 8];

  f32x16 o0, o1;
#pragma unroll
  for (int r = 0; r < 16; ++r) { o0[r] = 0.f; o1[r] = 0.f; }
  float m_r = -1e30f, l_r = 0.f;

  // K chunk c (0..511): LDS slot row=c>>3, slot=c&7 holds global chunk (c&7)^(row&7)
  const int kc0 = tid, kc1 = tid + 256;
  const int kr0 = kc0 >> 3, kg0 = (kc0 & 7) ^ (kr0 & 7);
  const int kr1 = kc1 >> 3, kg1 = (kc1 & 7) ^ (kr1 & 7);

  // prologue: stage tile 0
  GLDS16(Kh + bhBase + (size_t)kr0 * 64 + kg0 * 8, &Ks[0][0] + w * 512);
  GLDS16(Kh + bhBase + (size_t)kr1 * 64 + kg1 * 8, &Ks[0][0] + 2048 + w * 512);
  {
    const unsigned short* vs = Vh + bhBase + (size_t)lane * 64 + w * 16;
    short8 v0 = *(const short8*)vs, v1 = *(const short8*)(vs + 8);
#pragma unroll
    for (int k2 = 0; k2 < 8; ++k2) Vt[0][(w * 16 + k2) * 72 + lane] = (unsigned short)v0[k2];
#pragma unroll
    for (int k2 = 0; k2 < 8; ++k2) Vt[0][(w * 16 + 8 + k2) * 72 + lane] = (unsigned short)v1[k2];
  }
  __syncthreads();

  int cur = 0;
  for (int kt = 0; kt < Tt; kt += 64) {
    const bool last = (kt + 64 >= Tt);
    short8 v0, v1;
    if (!last) {
      // issue next-tile K staging + V global loads early (drained at end-of-tile barrier)
      GLDS16(Kh + bhBase + (size_t)(kt + 64 + kr0) * 64 + kg0 * 8, &Ks[cur ^ 1][0] + w * 512);
      GLDS16(Kh + bhBase + (size_t)(kt + 64 + kr1) * 64 + kg1 * 8, &Ks[cur ^ 1][0] + 2048 + w * 512);
      const unsigned short* vs = Vh + bhBase + (size_t)(kt + 64 + lane) * 64 + w * 16;
      v0 = *(const short8*)vs; v1 = *(const short8*)(vs + 8);
    }

    // ---- QK^T ----
    f32x16 p0, p1;
#pragma unroll
    for (int r = 0; r < 16; ++r) { p0[r] = 0.f; p1[r] = 0.f; }
    const unsigned short* Kc = &Ks[cur][0];
#pragma unroll
    for (int ks = 0; ks < 4; ++ks) {
      int row0 = l31, row1 = 32 + l31;
      short8 ka0 = *(const short8*)&Kc[row0 * 64 + (((ks * 2 + hi) ^ (row0 & 7)) * 8)];
      short8 ka1 = *(const short8*)&Kc[row1 * 64 + (((ks * 2 + hi) ^ (row1 & 7)) * 8)];
      p0 = __builtin_amdgcn_mfma_f32_32x32x16_bf16(ka0, qf[ks], p0, 0, 0, 0);
      p1 = __builtin_amdgcn_mfma_f32_32x32x16_bf16(ka1, qf[ks], p1, 0, 0, 0);
    }

    if (useMask) {
      int sg = s0 + l31;
#pragma unroll
      for (int r = 0; r < 16; ++r) {
        int tg = kt + (r & 3) + 8 * (r >> 2) + 4 * hi;
        if (mask[(size_t)sg * Tt + tg] == 0)      p0[r] = -1e30f;
        if (mask[(size_t)sg * Tt + tg + 32] == 0) p1[r] = -1e30f;
      }
    }

    // ---- online softmax (raw-score domain; lane owns full row with partner lane^32) ----
    float pmax = p0[0];
#pragma unroll
    for (int r = 1; r < 16; ++r) pmax = fmaxf(pmax, p0[r]);
#pragma unroll
    for (int r = 0; r < 16; ++r) pmax = fmaxf(pmax, p1[r]);
    pmax = fmaxf(pmax, __shfl_xor(pmax, 32));     // partner half (coalescing-safe)

    if (!__all(pmax - m_r <= 44.0f)) {           // T13 defer-max (P bounded by ~2^8)
      float mnew = fmaxf(m_r, pmax);
      float alpha = EXP2((m_r - mnew) * SCL);    // m_r=-1e30 first tile -> alpha=0
      l_r *= alpha;
#pragma unroll
      for (int r = 0; r < 16; ++r) {
        int sr = (r & 3) + 8 * (r >> 2) + 4 * hi;
        float ar = __shfl(alpha, sr);
        o0[r] *= ar; o1[r] *= ar;
      }
      m_r = mnew;
    }
    float mm = m_r * SCL;
    float ps = 0.f;
#pragma unroll
    for (int r = 0; r < 16; ++r) { p0[r] = EXP2(fmaf(p0[r], SCL, -mm)); ps += p0[r]; }
#pragma unroll
    for (int r = 0; r < 16; ++r) { p1[r] = EXP2(fmaf(p1[r], SCL, -mm)); ps += p1[r]; }
    l_r += ps + __shfl_xor(ps, 32);               // own + partner (coalescing-safe)

    // ---- pack P to PV A-fragments (cvt_pk + permlane32_swap, no LDS) ----
    short8 pa[4];
#define PACKKS(ks, PV)                                                         \
    {                                                                          \
      unsigned a0, a1, b0, b1; const int bse = 8 * ((ks) & 1);                 \
      CVTPK(a0, PV[bse + 0], PV[bse + 1]);                                     \
      CVTPK(a1, PV[bse + 2], PV[bse + 3]);                                     \
      CVTPK(b0, PV[bse + 4], PV[bse + 5]);                                     \
      CVTPK(b1, PV[bse + 6], PV[bse + 7]);                                     \
      PLSWAP(a0, b0); PLSWAP(a1, b1);                                          \
      union { unsigned u[4]; short8 s; } cc;                                   \
      cc.u[0] = a0; cc.u[1] = a1; cc.u[2] = b0; cc.u[3] = b1;                  \
      pa[ks] = cc.s;                                                           \
    }
    PACKKS(0, p0) PACKKS(1, p0) PACKKS(2, p1) PACKKS(3, p1)
#undef PACKKS

    // ---- PV: O += P * V  (B-frag = V^T rows, b128 at bank floor) ----
    const unsigned short* Vc = &Vt[cur][0];
#pragma unroll
    for (int ks = 0; ks < 4; ++ks) {
      short8 vf0 = *(const short8*)&Vc[(l31) * 72 + ks * 16 + hi * 8];
      short8 vf1 = *(const short8*)&Vc[(32 + l31) * 72 + ks * 16 + hi * 8];
      o0 = __builtin_amdgcn_mfma_f32_32x32x16_bf16(pa[ks], vf0, o0, 0, 0, 0);
      o1 = __builtin_amdgcn_mfma_f32_32x32x16_bf16(pa[ks], vf1, o1, 0, 0, 0);
    }

    if (!last) {
      // write prefetched V regs into next buffer (before barrier)
#pragma unroll
      for (int k2 = 0; k2 < 8; ++k2) Vt[cur ^ 1][(w * 16 + k2) * 72 + lane] = (unsigned short)v0[k2];
#pragma unroll
      for (int k2 = 0; k2 < 8; ++k2) Vt[cur ^ 1][(w * 16 + 8 + k2) * 72 + lane] = (unsigned short)v1[k2];
    }
    __syncthreads();
    cur ^= 1;
  }

  // ---- epilogue ----
  const int b = bh >> 4, h = bh & 15;
  float linv = l_r > 0.f ? 1.0f / l_r : 0.f;
#pragma unroll
  for (int r = 0; r < 16; ++r) {
    int sr = (r & 3) + 8 * (r >> 2) + 4 * hi;
    float li = __shfl(linv, sr);
    size_t rowbase = (size_t)(b * Ss + s0 + sr) * Ee + h * 64;
    Ob[rowbase + l31]      = f2bf(o0[r] * li);
    Ob[rowbase + 32 + l31] = f2bf(o1[r] * li);
  }
}

extern "C" void kernel_launch(void* const* d_in, const int* in_sizes, int n_in,
                              void* d_out, int out_size, void* d_ws, size_t ws_size,
                              hipStream_t stream) {
  const float* q   = (const float*)d_in[0];
  const float* k   = (const float*)d_in[1];
  const float* v   = (const float*)d_in[2];
  const int*  msk  = (const int*)d_in[3];
  const float* Wq  = (const float*)d_in[4];
  const float* bq  = (const float*)d_in[5];
  const float* Wk  = (const float*)d_in[6];
  const float* bk  = (const float*)d_in[7];
  const float* Wv  = (const float*)d_in[8];
  const float* bv  = (const float*)d_in[9];
  const float* Wo  = (const float*)d_in[10];
  const float* bo  = (const float*)d_in[11];
  float* out = (float*)d_out;

  char* ws = (char*)d_ws;
  unsigned short* Xq  = (unsigned short*)(ws + OFF_XQ);
  unsigned short* Xk  = (unsigned short*)(ws + OFF_XK);
  unsigned short* Xv  = (unsigned short*)(ws + OFF_XV);
  unsigned short* Wqb = (unsigned short*)(ws + OFF_WQ);
  unsigned short* Wkb = (unsigned short*)(ws + OFF_WK);
  unsigned short* Wvb = (unsigned short*)(ws + OFF_WV);
  unsigned short* Wob = (unsigned short*)(ws + OFF_WO);
  unsigned short* Qh  = (unsigned short*)(ws + OFF_QH);
  unsigned short* Kh  = (unsigned short*)(ws + OFF_KH);
  unsigned short* Vh  = (unsigned short*)(ws + OFF_VH);
  unsigned short* Ob  = (unsigned short*)(ws + OFF_OB);
  int* flagZero       = (int*)(ws + OFF_FLAG);

  hipMemsetAsync(flagZero, 0, 4, stream);
  prep_kernel<<<4096, 256, 0, stream>>>(q, k, v, Wq, Wk, Wv, Wo, msk,
                                        Xq, Xk, Xv, Wqb, Wkb, Wvb, Wob, flagZero);
  gemm_qkv<<<dim3(8, 32, 3), 256, 0, stream>>>(Xq, Xk, Xv, Wqb, Wkb, Wvb,
                                               bq, bk, bv, Qh, Kh, Vh);
  attn_kernel<<<dim3(16, 32), 256, 0, stream>>>(Qh, Kh, Vh, msk, flagZero, Ob);
  gemm_out<<<dim3(8, 32), 256, 0, stream>>>(Ob, Wob, bo, out);
}